// Round 15
// baseline (65.589 us; speedup 1.0000x reference)
//
#include <hip/hip_runtime.h>
#include <hip/hip_bf16.h>

#define TDIM 1024
#define KDIM 32

typedef short bf16x8 __attribute__((ext_vector_type(8)));
typedef float f32x4  __attribute__((ext_vector_type(4)));

// RNE-ish pack (round-half-up): 3 VALU. Used only off the hot loop.
__device__ __forceinline__ unsigned pk_pair(float lo, float hi) {
    unsigned ul = __float_as_uint(lo) + 0x8000u;
    unsigned uh = __float_as_uint(hi) + 0x8000u;
    return __builtin_amdgcn_perm(uh, ul, 0x07060302u);
}
// truncating pack: 1 VALU. Hot-loop only (bias ~-0.1%/use, ledger-safe).
__device__ __forceinline__ unsigned tk_pair(float lo, float hi) {
    return __builtin_amdgcn_perm(__float_as_uint(hi), __float_as_uint(lo), 0x07060302u);
}
__device__ __forceinline__ bf16x8 pk8(f32x4 lo, f32x4 hi) {
    union { unsigned u[4]; bf16x8 v; } x;
    x.u[0] = pk_pair(lo[0], lo[1]); x.u[1] = pk_pair(lo[2], lo[3]);
    x.u[2] = pk_pair(hi[0], hi[1]); x.u[3] = pk_pair(hi[2], hi[3]);
    return x.v;
}
__device__ __forceinline__ bf16x8 tk8(f32x4 lo, f32x4 hi) {
    union { unsigned u[4]; bf16x8 v; } x;
    x.u[0] = tk_pair(lo[0], lo[1]); x.u[1] = tk_pair(lo[2], lo[3]);
    x.u[2] = tk_pair(hi[0], hi[1]); x.u[3] = tk_pair(hi[2], hi[3]);
    return x.v;
}

__device__ __forceinline__ int read_len(const int* __restrict__ lengths32, int b) {
    // int64 little-endian: int32 view at odd index 1 is high word of lengths[0] == 0.
    // int32: lengths[1] in [1,1024], never 0.  (verified rounds 1-14)
    const bool is64 = (lengths32[1] == 0);
    int len = is64 ? lengths32[2 * b] : lengths32[b];
    return len < 1 ? 1 : (len > TDIM ? TDIM : len);
}

// ---------------- K1: per-(batch, chunk) 32x32 product matrix -------------
// P_new = E^T (D_t P_old): A operand = bf16(E^T), STATIC (packed once);
// per step: B = trunc-pack(d (.) C) = 16 mul + 8 perm, then 4 MFMA (~30 VALU).
// R15: CHS=32/NCH=32 -> ~8200 alive waves ~= full wave capacity; 16KB LDS
// block, no min-wave bound -> 8 blocks/CU. Issue-efficiency via TLP.
template<int CHS, int NCH>
__global__ __launch_bounds__(256) void crf_chunk_kernel(
    const float* __restrict__ emissions,    // [B, T, K]
    const int*   __restrict__ lengths32,
    const float* __restrict__ transitions,  // [K, K]
    unsigned int* __restrict__ Pout,        // [B][NCH][1024] bf16 as 512 dwords
    int*          __restrict__ toteOut)     // [B][NCH]
{
    __shared__ float lds_all[4][CHS * KDIM];
    const int wid  = threadIdx.x >> 6;
    const int lane = threadIdx.x & 63;
    const int n    = lane & 15;
    const int g    = (lane >> 4) & 3;
    const int c    = blockIdx.x * 4 + wid;
    const int b    = blockIdx.y;

    const int len = read_len(lengths32, b);
    const int t0  = 1 + c * CHS;
    int count = len - t0; count = count > CHS ? CHS : count;
    if (count <= 0) return;                  // dead chunk -> free the slot

    // ---- stage CHS emission rows into this wave's LDS slice (async DMA) ----
    int base_t = t0, shift = 0;
    if (t0 + CHS > TDIM) { base_t = TDIM - CHS; shift = t0 - base_t; }
    const float* src = emissions + ((size_t)b * TDIM + base_t) * KDIM;
    float* myl = lds_all[wid];
    constexpr int NSEG = CHS * KDIM / 256;   // 1KB segments
#pragma unroll
    for (int s = 0; s < NSEG; ++s)
        __builtin_amdgcn_global_load_lds(
            (const __attribute__((address_space(1))) void*)(src + s * 256 + lane * 4),
            (__attribute__((address_space(3))) void*)(myl + s * 256), 16, 0, 0);

    // static A operand: bf16(E^T), element e <-> contraction row rho(g,e)
    f32x4 Ef00, Ef01, Ef10, Ef11;
#pragma unroll
    for (int e = 0; e < 4; ++e) {
        Ef00[e] = __expf(transitions[(4 * g + e) * KDIM + n]);
        Ef01[e] = __expf(transitions[(16 + 4 * g + e) * KDIM + n]);
        Ef10[e] = __expf(transitions[(4 * g + e) * KDIM + 16 + n]);
        Ef11[e] = __expf(transitions[(16 + 4 * g + e) * KDIM + 16 + n]);
    }
    const bf16x8 A0 = pk8(Ef00, Ef01);   // rows n      (RNE: reused every step)
    const bf16x8 A1 = pk8(Ef10, Ef11);   // rows 16+n

    asm volatile("s_waitcnt vmcnt(0)" ::: "memory");
    __builtin_amdgcn_sched_barrier(0);

    // ---- exp pre-pass in place (per-wave slice) ----
    f32x4* mylv = (f32x4*)myl;
#pragma unroll
    for (int r = 0; r < NSEG; ++r) {
        f32x4 v = mylv[r * 64 + lane];
#pragma unroll
        for (int e = 0; e < 4; ++e) v[e] = __expf(v[e]);
        mylv[r * 64 + lane] = v;
    }
    asm volatile("s_waitcnt lgkmcnt(0)" ::: "memory");
    __builtin_amdgcn_sched_barrier(0);

    // ---- running product in C-frags ----
    f32x4 C00, C01, C10, C11;
#pragma unroll
    for (int q = 0; q < 4; ++q) {
        float d = (4 * g + q == n) ? 1.0f : 0.0f;
        C00[q] = d; C11[q] = d; C01[q] = 0.0f; C10[q] = 0.0f;
    }
    float sf = 1.0f; int pend = 0, tote = 0;
    const f32x4 zero = {0.0f, 0.0f, 0.0f, 0.0f};

    // d values for this lane group: e0 = d[4g..4g+3], e1 = d[16+4g..16+4g+3]
    // B0 = trunc(e0 (.) C00, e1 (.) C10), B1 = trunc(e0 (.) C01, e1 (.) C11)
    auto STEP = [&](const f32x4& e0, const f32x4& e1) {
        f32x4 t0v = C00 * e0, t1v = C10 * e1, t2v = C01 * e0, t3v = C11 * e1;
        bf16x8 B0 = tk8(t0v, t1v), B1 = tk8(t2v, t3v);
        C00 = __builtin_amdgcn_mfma_f32_16x16x32_bf16(A0, B0, zero, 0, 0, 0);
        C01 = __builtin_amdgcn_mfma_f32_16x16x32_bf16(A0, B1, zero, 0, 0, 0);
        C10 = __builtin_amdgcn_mfma_f32_16x16x32_bf16(A1, B0, zero, 0, 0, 0);
        C11 = __builtin_amdgcn_mfma_f32_16x16x32_bf16(A1, B1, zero, 0, 0, 0);
    };
    auto RESCALE = [&]() {
        int bits = __builtin_amdgcn_readfirstlane(__float_as_int(C00[0]));
        pend = ((bits >> 23) & 255) - 127;
        sf = __uint_as_float((unsigned)(127 - pend) << 23);
    };

    if (count == CHS) {
        // depth-2 LDS read pipeline, static slot = u&1
        f32x4 pipe[2][2];
        pipe[0][0] = mylv[0 * 8 + g]; pipe[0][1] = mylv[0 * 8 + 4 + g];
        pipe[1][0] = mylv[1 * 8 + g]; pipe[1][1] = mylv[1 * 8 + 4 + g];
        constexpr int NQ = CHS / 4;
        for (int tq = 0; tq < NQ; ++tq) {
#pragma unroll
            for (int u = 0; u < 4; ++u) {
                const int s = u & 1;
                f32x4 e0 = pipe[s][0], e1 = pipe[s][1];
                int tl = 4 * tq + u + 2; if (tl > CHS - 1) tl = CHS - 1;
                pipe[s][0] = mylv[tl * 8 + g];
                pipe[s][1] = mylv[tl * 8 + 4 + g];
                if (u == 0) {
#pragma unroll
                    for (int e = 0; e < 4; ++e) { e0[e] *= sf; e1[e] *= sf; }
                    tote += pend;
                }
                STEP(e0, e1);
                if (u == 3) RESCALE();
            }
        }
    } else {
        // boundary chunk: per-step fold + rescale
        for (int tau = 0; tau < count; ++tau) {
            f32x4 e0 = mylv[(tau + shift) * 8 + g];
            f32x4 e1 = mylv[(tau + shift) * 8 + 4 + g];
#pragma unroll
            for (int e = 0; e < 4; ++e) { e0[e] *= sf; e1[e] *= sf; }
            tote += pend;
            STEP(e0, e1);
            RESCALE();
        }
    }

    // store bf16 col-major: dword idx = col*16 + row/2 (RNE pack, once)
    unsigned int* outP = Pout + ((size_t)b * NCH + c) * 512;
#pragma unroll
    for (int p = 0; p < 2; ++p) {
        int q = 2 * p;
        outP[n * 16        + (4 * g + q) / 2]      = pk_pair(C00[q], C00[q + 1]);
        outP[(16 + n) * 16 + (4 * g + q) / 2]      = pk_pair(C01[q], C01[q + 1]);
        outP[n * 16        + (16 + 4 * g + q) / 2] = pk_pair(C10[q], C10[q + 1]);
        outP[(16 + n) * 16 + (16 + 4 * g + q) / 2] = pk_pair(C11[q], C11[q + 1]);
    }
    if (lane == 0) toteOut[b * NCH + c] = tote;
}

// ---------------- K2: chain chunk matrices through alpha ------------------
template<int NCH, int CHS>
__global__ __launch_bounds__(64) void crf_combine_kernel(
    const float* __restrict__ emissions,
    const int*   __restrict__ lengths32,
    const float* __restrict__ head_t,
    const float* __restrict__ last_t,
    const unsigned short* __restrict__ Pbuf,  // [B][NCH][1024] bf16 col-major
    const int*   __restrict__ toteBuf,
    float*       __restrict__ out)
{
    const int b    = blockIdx.x;
    const int lane = threadIdx.x;
    const int j    = lane & 31;

    const int len = read_len(lengths32, b);
    int nAlive = (len - 1 + CHS - 1) / CHS;
    if (nAlive > NCH) nAlive = NCH;

    float alpha = __expf(head_t[j] + emissions[(size_t)b * TDIM * KDIM + j]);
    int tote = 0;

    const char* base = (const char*)(Pbuf + (size_t)b * NCH * 1024);

    auto LOADC = [&](int cix, uint4 dst[4]) {
        int cc = cix < NCH ? cix : NCH - 1;
        const uint4* pc = (const uint4*)(base + (size_t)cc * 2048 + (size_t)j * 64);
#pragma unroll
        for (int w = 0; w < 4; ++w) dst[w] = pc[w];
    };

    uint4 cur[4], nx1[4];
    LOADC(0, cur);
    LOADC(1, nx1);

    for (int cix = 0; cix < nAlive; ++cix) {
        uint4 nx2[4];
        LOADC(cix + 2, nx2);

        float a0 = 0.0f, a1 = 0.0f;
#pragma unroll
        for (int w = 0; w < 4; ++w) {
            unsigned d[4] = {cur[w].x, cur[w].y, cur[w].z, cur[w].w};
#pragma unroll
            for (int h = 0; h < 4; ++h) {
                int r = w * 8 + h * 2;
                float plo = __uint_as_float(d[h] << 16);           // row r,   col j
                float phi = __uint_as_float(d[h] & 0xffff0000u);   // row r+1, col j
                float al  = __int_as_float(__builtin_amdgcn_readlane(__float_as_int(alpha), r));
                float ah  = __int_as_float(__builtin_amdgcn_readlane(__float_as_int(alpha), r + 1));
                a0 = fmaf(plo, al, a0);
                a1 = fmaf(phi, ah, a1);
            }
        }
        float acc = a0 + a1;
        int bits = __builtin_amdgcn_readfirstlane(__float_as_int(acc));
        int s = ((bits >> 23) & 255) - 127;
        alpha = acc * __uint_as_float((unsigned)(127 - s) << 23);
        tote += s + toteBuf[b * NCH + cix];
#pragma unroll
        for (int w = 0; w < 4; ++w) { cur[w] = nx1[w]; nx1[w] = nx2[w]; }
    }

    float pp = alpha * __expf(last_t[j]);
#pragma unroll
    for (int mm = 16; mm >= 1; mm >>= 1)
        pp += __shfl_xor(pp, mm, 64);

    if (lane == 0)
        out[b] = __logf(pp) + (float)tote * 0.69314718055994531f;
}

extern "C" void kernel_launch(void* const* d_in, const int* in_sizes, int n_in,
                              void* d_out, int out_size, void* d_ws, size_t ws_size,
                              hipStream_t stream)
{
    const float* emissions   = (const float*)d_in[0];
    const int*   lengths     = (const int*)d_in[1];
    const float* transitions = (const float*)d_in[2];
    const float* head_t      = (const float*)d_in[3];
    const float* last_t      = (const float*)d_in[4];
    float* out = (float*)d_out;
    const int B = out_size;  // 512

    unsigned int* Pbuf = (unsigned int*)d_ws;

    const size_t need32 = (size_t)B * 32 * 2048 + (size_t)B * 32 * 4;
    const size_t need16 = (size_t)B * 16 * 2048 + (size_t)B * 16 * 4;
    if (ws_size >= need32) {
        int* toteBf = (int*)((char*)d_ws + (size_t)B * 32 * 2048);
        dim3 g1(8, B);    // 8 blocks x 4 waves = 32 chunks of 32 steps
        crf_chunk_kernel<32, 32><<<g1, 256, 0, stream>>>(emissions, lengths, transitions, Pbuf, toteBf);
        crf_combine_kernel<32, 32><<<B, 64, 0, stream>>>(emissions, lengths, head_t, last_t,
                                                         (const unsigned short*)Pbuf, toteBf, out);
    } else {
        int* toteBf = (int*)((char*)d_ws + (size_t)B * 16 * 2048);
        dim3 g1(4, B);    // 4 blocks x 4 waves = 16 chunks of 64 steps
        crf_chunk_kernel<64, 16><<<g1, 256, 0, stream>>>(emissions, lengths, transitions, Pbuf, toteBf);
        crf_combine_kernel<16, 64><<<B, 64, 0, stream>>>(emissions, lengths, head_t, last_t,
                                                         (const unsigned short*)Pbuf, toteBf, out);
    }
}

// Round 16
// 50.822 us; speedup vs baseline: 1.2905x; 1.2905x over previous
//
#include <hip/hip_runtime.h>
#include <hip/hip_bf16.h>

#define TDIM 1024
#define KDIM 32

typedef short bf16x8 __attribute__((ext_vector_type(8)));
typedef float f32x4  __attribute__((ext_vector_type(4)));
typedef float f32x2  __attribute__((ext_vector_type(2)));

// RNE-ish pack (round-half-up): 3 VALU. Used only off the hot loop.
__device__ __forceinline__ unsigned pk_pair(float lo, float hi) {
    unsigned ul = __float_as_uint(lo) + 0x8000u;
    unsigned uh = __float_as_uint(hi) + 0x8000u;
    return __builtin_amdgcn_perm(uh, ul, 0x07060302u);
}
// truncating pack: 1 VALU. Hot-loop only (bias ~-0.1%/use, ledger-safe).
__device__ __forceinline__ unsigned tk_pair(float lo, float hi) {
    return __builtin_amdgcn_perm(__float_as_uint(hi), __float_as_uint(lo), 0x07060302u);
}
__device__ __forceinline__ bf16x8 pk8(f32x4 lo, f32x4 hi) {
    union { unsigned u[4]; bf16x8 v; } x;
    x.u[0] = pk_pair(lo[0], lo[1]); x.u[1] = pk_pair(lo[2], lo[3]);
    x.u[2] = pk_pair(hi[0], hi[1]); x.u[3] = pk_pair(hi[2], hi[3]);
    return x.v;
}
__device__ __forceinline__ bf16x8 tk8(f32x4 lo, f32x4 hi) {
    union { unsigned u[4]; bf16x8 v; } x;
    x.u[0] = tk_pair(lo[0], lo[1]); x.u[1] = tk_pair(lo[2], lo[3]);
    x.u[2] = tk_pair(hi[0], hi[1]); x.u[3] = tk_pair(hi[2], hi[3]);
    return x.v;
}

// element-wise f32 multiply expressed as <2 x float> ops so gfx950 ISel can
// select v_pk_mul_f32 (VOP3P packed dual-FP32; halves per-step mul count).
__device__ __forceinline__ f32x4 dmul(f32x4 c, f32x4 e) {
    union U { f32x4 v; f32x2 h[2]; };
    U uc, ue, r;
    uc.v = c; ue.v = e;
    r.h[0] = uc.h[0] * ue.h[0];
    r.h[1] = uc.h[1] * ue.h[1];
    return r.v;
}
__device__ __forceinline__ f32x4 dscale(f32x4 c, float s) {
    union U { f32x4 v; f32x2 h[2]; };
    U uc, r;
    uc.v = c;
    f32x2 sv = {s, s};
    r.h[0] = uc.h[0] * sv;
    r.h[1] = uc.h[1] * sv;
    return r.v;
}

__device__ __forceinline__ int read_len(const int* __restrict__ lengths32, int b) {
    // int64 little-endian: int32 view at odd index 1 is high word of lengths[0] == 0.
    // int32: lengths[1] in [1,1024], never 0.  (verified rounds 1-15)
    const bool is64 = (lengths32[1] == 0);
    int len = is64 ? lengths32[2 * b] : lengths32[b];
    return len < 1 ? 1 : (len > TDIM ? TDIM : len);
}

// ---------------- K1: per-(batch, chunk) 32x32 product matrix -------------
// P_new = E^T (D_t P_old): A operand = bf16(E^T), STATIC (packed once);
// per step: B = trunc-pack(d (.) C) = 8 pk_mul + 8 perm, then 4 MFMA.
// R1-R15 conclusion: machine issues ~0.35 inst/cyc/CU in all configs
// (DVFS-floored issue roofline) -> duration ~ total instruction count.
template<int CHS, int NCH>
__global__ __launch_bounds__(256, 4) void crf_chunk_kernel(
    const float* __restrict__ emissions,    // [B, T, K]
    const int*   __restrict__ lengths32,
    const float* __restrict__ transitions,  // [K, K]
    unsigned int* __restrict__ Pout,        // [B][NCH][1024] bf16 as 512 dwords
    int*          __restrict__ toteOut)     // [B][NCH]
{
    __shared__ float lds_all[4][CHS * KDIM];
    const int wid  = threadIdx.x >> 6;
    const int lane = threadIdx.x & 63;
    const int n    = lane & 15;
    const int g    = (lane >> 4) & 3;
    const int c    = blockIdx.x * 4 + wid;
    const int b    = blockIdx.y;

    const int len = read_len(lengths32, b);
    const int t0  = 1 + c * CHS;
    int count = len - t0; count = count > CHS ? CHS : count;
    if (count <= 0) return;                  // dead chunk

    // ---- stage CHS emission rows into this wave's LDS slice (async DMA) ----
    int base_t = t0, shift = 0;
    if (t0 + CHS > TDIM) { base_t = TDIM - CHS; shift = t0 - base_t; }
    const float* src = emissions + ((size_t)b * TDIM + base_t) * KDIM;
    float* myl = lds_all[wid];
    constexpr int NSEG = CHS * KDIM / 256;   // 1KB segments
#pragma unroll
    for (int s = 0; s < NSEG; ++s)
        __builtin_amdgcn_global_load_lds(
            (const __attribute__((address_space(1))) void*)(src + s * 256 + lane * 4),
            (__attribute__((address_space(3))) void*)(myl + s * 256), 16, 0, 0);

    // static A operand: bf16(E^T), element e <-> contraction row rho(g,e)
    f32x4 Ef00, Ef01, Ef10, Ef11;
#pragma unroll
    for (int e = 0; e < 4; ++e) {
        Ef00[e] = __expf(transitions[(4 * g + e) * KDIM + n]);
        Ef01[e] = __expf(transitions[(16 + 4 * g + e) * KDIM + n]);
        Ef10[e] = __expf(transitions[(4 * g + e) * KDIM + 16 + n]);
        Ef11[e] = __expf(transitions[(16 + 4 * g + e) * KDIM + 16 + n]);
    }
    const bf16x8 A0 = pk8(Ef00, Ef01);   // rows n      (RNE: reused every step)
    const bf16x8 A1 = pk8(Ef10, Ef11);   // rows 16+n

    asm volatile("s_waitcnt vmcnt(0)" ::: "memory");
    __builtin_amdgcn_sched_barrier(0);

    // ---- exp pre-pass in place (per-wave slice) ----
    f32x4* mylv = (f32x4*)myl;
#pragma unroll
    for (int r = 0; r < NSEG; ++r) {
        f32x4 v = mylv[r * 64 + lane];
#pragma unroll
        for (int e = 0; e < 4; ++e) v[e] = __expf(v[e]);
        mylv[r * 64 + lane] = v;
    }
    asm volatile("s_waitcnt lgkmcnt(0)" ::: "memory");
    __builtin_amdgcn_sched_barrier(0);

    // ---- running product in C-frags ----
    f32x4 C00, C01, C10, C11;
#pragma unroll
    for (int q = 0; q < 4; ++q) {
        float d = (4 * g + q == n) ? 1.0f : 0.0f;
        C00[q] = d; C11[q] = d; C01[q] = 0.0f; C10[q] = 0.0f;
    }
    float sf = 1.0f; int pend = 0, tote = 0;
    const f32x4 zero = {0.0f, 0.0f, 0.0f, 0.0f};

    // d values for this lane group: e0 = d[4g..4g+3], e1 = d[16+4g..16+4g+3]
    // B0 = trunc(e0 (.) C00, e1 (.) C10), B1 = trunc(e0 (.) C01, e1 (.) C11)
    auto STEP = [&](const f32x4& e0, const f32x4& e1) {
        f32x4 t0v = dmul(C00, e0), t1v = dmul(C10, e1);
        f32x4 t2v = dmul(C01, e0), t3v = dmul(C11, e1);
        bf16x8 B0 = tk8(t0v, t1v), B1 = tk8(t2v, t3v);
        C00 = __builtin_amdgcn_mfma_f32_16x16x32_bf16(A0, B0, zero, 0, 0, 0);
        C01 = __builtin_amdgcn_mfma_f32_16x16x32_bf16(A0, B1, zero, 0, 0, 0);
        C10 = __builtin_amdgcn_mfma_f32_16x16x32_bf16(A1, B0, zero, 0, 0, 0);
        C11 = __builtin_amdgcn_mfma_f32_16x16x32_bf16(A1, B1, zero, 0, 0, 0);
    };
    auto RESCALE = [&]() {
        int bits = __builtin_amdgcn_readfirstlane(__float_as_int(C00[0]));
        pend = ((bits >> 23) & 255) - 127;
        sf = __uint_as_float((unsigned)(127 - pend) << 23);
    };

    if (count == CHS) {
        // depth-2 LDS read pipeline, static slot = u&1
        f32x4 pipe[2][2];
        pipe[0][0] = mylv[0 * 8 + g]; pipe[0][1] = mylv[0 * 8 + 4 + g];
        pipe[1][0] = mylv[1 * 8 + g]; pipe[1][1] = mylv[1 * 8 + 4 + g];
        constexpr int NQ = CHS / 4;
        for (int tq = 0; tq < NQ; ++tq) {
#pragma unroll
            for (int u = 0; u < 4; ++u) {
                const int s = u & 1;
                f32x4 e0 = pipe[s][0], e1 = pipe[s][1];
                int tl = 4 * tq + u + 2; if (tl > CHS - 1) tl = CHS - 1;
                pipe[s][0] = mylv[tl * 8 + g];
                pipe[s][1] = mylv[tl * 8 + 4 + g];
                if (u == 0) {
                    e0 = dscale(e0, sf);
                    e1 = dscale(e1, sf);
                    tote += pend;
                }
                STEP(e0, e1);
                if (u == 3) RESCALE();
            }
        }
    } else {
        // boundary chunk: per-step fold + rescale
        for (int tau = 0; tau < count; ++tau) {
            f32x4 e0 = mylv[(tau + shift) * 8 + g];
            f32x4 e1 = mylv[(tau + shift) * 8 + 4 + g];
            e0 = dscale(e0, sf);
            e1 = dscale(e1, sf);
            tote += pend;
            STEP(e0, e1);
            RESCALE();
        }
    }

    // store bf16 col-major: dword idx = col*16 + row/2 (RNE pack, once)
    unsigned int* outP = Pout + ((size_t)b * NCH + c) * 512;
#pragma unroll
    for (int p = 0; p < 2; ++p) {
        int q = 2 * p;
        outP[n * 16        + (4 * g + q) / 2]      = pk_pair(C00[q], C00[q + 1]);
        outP[(16 + n) * 16 + (4 * g + q) / 2]      = pk_pair(C01[q], C01[q + 1]);
        outP[n * 16        + (16 + 4 * g + q) / 2] = pk_pair(C10[q], C10[q + 1]);
        outP[(16 + n) * 16 + (16 + 4 * g + q) / 2] = pk_pair(C11[q], C11[q + 1]);
    }
    if (lane == 0) toteOut[b * NCH + c] = tote;
}

// ---------------- K2: chain chunk matrices through alpha ------------------
template<int NCH, int CHS>
__global__ __launch_bounds__(64) void crf_combine_kernel(
    const float* __restrict__ emissions,
    const int*   __restrict__ lengths32,
    const float* __restrict__ head_t,
    const float* __restrict__ last_t,
    const unsigned short* __restrict__ Pbuf,  // [B][NCH][1024] bf16 col-major
    const int*   __restrict__ toteBuf,
    float*       __restrict__ out)
{
    const int b    = blockIdx.x;
    const int lane = threadIdx.x;
    const int j    = lane & 31;

    const int len = read_len(lengths32, b);
    int nAlive = (len - 1 + CHS - 1) / CHS;
    if (nAlive > NCH) nAlive = NCH;

    float alpha = __expf(head_t[j] + emissions[(size_t)b * TDIM * KDIM + j]);
    int tote = 0;

    const char* base = (const char*)(Pbuf + (size_t)b * NCH * 1024);

    auto LOADC = [&](int cix, uint4 dst[4]) {
        int cc = cix < NCH ? cix : NCH - 1;
        const uint4* pc = (const uint4*)(base + (size_t)cc * 2048 + (size_t)j * 64);
#pragma unroll
        for (int w = 0; w < 4; ++w) dst[w] = pc[w];
    };

    uint4 cur[4], nx1[4];
    LOADC(0, cur);
    LOADC(1, nx1);

    for (int cix = 0; cix < nAlive; ++cix) {
        uint4 nx2[4];
        LOADC(cix + 2, nx2);

        float a0 = 0.0f, a1 = 0.0f;
#pragma unroll
        for (int w = 0; w < 4; ++w) {
            unsigned d[4] = {cur[w].x, cur[w].y, cur[w].z, cur[w].w};
#pragma unroll
            for (int h = 0; h < 4; ++h) {
                int r = w * 8 + h * 2;
                float plo = __uint_as_float(d[h] << 16);           // row r,   col j
                float phi = __uint_as_float(d[h] & 0xffff0000u);   // row r+1, col j
                float al  = __int_as_float(__builtin_amdgcn_readlane(__float_as_int(alpha), r));
                float ah  = __int_as_float(__builtin_amdgcn_readlane(__float_as_int(alpha), r + 1));
                a0 = fmaf(plo, al, a0);
                a1 = fmaf(phi, ah, a1);
            }
        }
        float acc = a0 + a1;
        int bits = __builtin_amdgcn_readfirstlane(__float_as_int(acc));
        int s = ((bits >> 23) & 255) - 127;
        alpha = acc * __uint_as_float((unsigned)(127 - s) << 23);
        tote += s + toteBuf[b * NCH + cix];
#pragma unroll
        for (int w = 0; w < 4; ++w) { cur[w] = nx1[w]; nx1[w] = nx2[w]; }
    }

    float pp = alpha * __expf(last_t[j]);
#pragma unroll
    for (int mm = 16; mm >= 1; mm >>= 1)
        pp += __shfl_xor(pp, mm, 64);

    if (lane == 0)
        out[b] = __logf(pp) + (float)tote * 0.69314718055994531f;
}

extern "C" void kernel_launch(void* const* d_in, const int* in_sizes, int n_in,
                              void* d_out, int out_size, void* d_ws, size_t ws_size,
                              hipStream_t stream)
{
    const float* emissions   = (const float*)d_in[0];
    const int*   lengths     = (const int*)d_in[1];
    const float* transitions = (const float*)d_in[2];
    const float* head_t      = (const float*)d_in[3];
    const float* last_t      = (const float*)d_in[4];
    float* out = (float*)d_out;
    const int B = out_size;  // 512

    unsigned int* Pbuf = (unsigned int*)d_ws;

    const size_t need16 = (size_t)B * 16 * 2048 + (size_t)B * 16 * 4;
    if (ws_size >= need16) {
        int* toteBf = (int*)((char*)d_ws + (size_t)B * 16 * 2048);
        dim3 g1(4, B);    // 4 blocks x 4 waves = 16 chunks of 64 steps
        crf_chunk_kernel<64, 16><<<g1, 256, 0, stream>>>(emissions, lengths, transitions, Pbuf, toteBf);
        crf_combine_kernel<16, 64><<<B, 64, 0, stream>>>(emissions, lengths, head_t, last_t,
                                                         (const unsigned short*)Pbuf, toteBf, out);
    } else {
        int* toteBf = (int*)((char*)d_ws + (size_t)B * 8 * 2048);
        dim3 g1(2, B);    // 2 blocks x 4 waves = 8 chunks of 128 steps
        crf_chunk_kernel<128, 8><<<g1, 256, 0, stream>>>(emissions, lengths, transitions, Pbuf, toteBf);
        crf_combine_kernel<8, 128><<<B, 64, 0, stream>>>(emissions, lengths, head_t, last_t,
                                                         (const unsigned short*)Pbuf, toteBf, out);
    }
}